// Round 2
// baseline (1218.421 us; speedup 1.0000x reference)
//
#include <hip/hip_runtime.h>

// Bilinear 2x upsample, NHWC fp32.
// in : (8, 256, 256, 32)  = 64 MiB
// out: (8, 512, 512, 32)  = 256 MiB
//
// R4 = MEASUREMENT ROUND. Exact R2 memory behavior (no XCD swizzle, normal
// stores — the 309.2 us best) + a calibrated dead FMA chain (~220 us VALU)
// so this kernel rises above the ~166 us harness fills into the rocprof
// top-5. Goal: read this kernel's own FETCH_SIZE / WRITE_SIZE / dur_us to
// decide between "already at HBM roofline" and "read amplification".
// The pad does not touch memory; traffic counters reflect the R2 kernel.
// Pad will be removed next round.

#define IH 256
#define IW 256
#define OHW 512
#define C4 8        // 32 channels / 4 floats per float4

typedef float f4 __attribute__((ext_vector_type(4)));

__global__ __launch_bounds__(256) void bilinear2x_kernel(
    const float* __restrict__ img, float* __restrict__ out) {
    unsigned tid = blockIdx.x * 256u + threadIdx.x;

    unsigned c4 = tid & (C4 - 1);          // float4 index within channels
    unsigned ox = (tid >> 3) & (OHW - 1);  // output x
    unsigned j  = (tid >> 12) & (IH - 1);  // output y pair index: oy = 2j, 2j+1
    unsigned n  = tid >> 20;

    // x weights: gx = max(0.5*ox - 0.25, 0)
    float gx = fmaxf(0.5f * (float)ox - 0.25f, 0.0f);
    int x0 = (int)gx;                      // trunc == floor (gx >= 0)
    float w0 = gx - (float)x0;
    int x1 = x0 + (x0 < IW - 1);
    float w1 = 1.0f - w0;

    // input rows j-1, j, j+1 (clamped)
    int rA = (int)j - 1; rA = rA < 0 ? 0 : rA;
    int rB = (int)j;
    int rC = (int)j + 1; rC = rC > IH - 1 ? IH - 1 : rC;

    const f4* base = (const f4*)img;
    size_t nb = (size_t)n * (IH * IW * C4);
    const f4* pA = base + nb + (size_t)rA * (IW * C4);
    const f4* pB = base + nb + (size_t)rB * (IW * C4);
    const f4* pC = base + nb + (size_t)rC * (IW * C4);
    size_t o0 = (size_t)x0 * C4 + c4;
    size_t o1 = (size_t)x1 * C4 + c4;

    f4 a0 = pA[o0], a1 = pA[o1];
    f4 b0 = pB[o0], b1 = pB[o1];
    f4 c0 = pC[o0], c1 = pC[o1];

    // x-interpolate each row
    f4 ra = w1 * a0 + w0 * a1;
    f4 rb = w1 * b0 + w0 * b1;
    f4 rc = w1 * c0 + w0 * c1;

    // y-combine: even = 0.25*A + 0.75*B ; odd = 0.75*B + 0.25*C
    f4 re = 0.25f * ra + 0.75f * rb;
    f4 ro = 0.75f * rb + 0.25f * rc;

    // coalesced stores (normal, cached — R2 behavior)
    f4* ob = (f4*)out;
    size_t oe = (((size_t)n * OHW + 2 * j) * OHW + ox) * C4 + c4;
    ob[oe] = re;
    ob[oe + (size_t)OHW * C4] = ro;

    // --- calibrated VALU pad (measurement only; removed next round) ---
    // 2200 dependent FMAs: per SIMD ~128 waves x 2200 instr x 2 cyc
    // = ~563K cycles = ~235 us at 2.4 GHz. Kept live, touches no memory.
    float v0 = (float)threadIdx.x;
    const float m = 1.0000001f, a = 1e-7f;
#pragma unroll 1
    for (int it = 0; it < 2200; ++it) v0 = __builtin_fmaf(v0, m, a);
    asm volatile("" :: "v"(v0));
}

extern "C" void kernel_launch(void* const* d_in, const int* in_sizes, int n_in,
                              void* d_out, int out_size, void* d_ws, size_t ws_size,
                              hipStream_t stream) {
    const float* img = (const float*)d_in[0];
    float* out = (float*)d_out;
    // threads: 8 * 256(j) * 512(ox) * 8(c4) = 8,388,608
    const unsigned total = 8u * 256u * 512u * 8u;
    dim3 grid(total / 256u);
    dim3 block(256);
    bilinear2x_kernel<<<grid, block, 0, stream>>>(img, out);
}

// Round 4
// 320.145 us; speedup vs baseline: 3.8058x; 3.8058x over previous
//
#include <hip/hip_runtime.h>

// Bilinear 2x upsample, NHWC fp32.
// in : (8, 256, 256, 32)  = 64 MiB
// out: (8, 512, 512, 32)  = 256 MiB
//
// R5 (re-run; previous attempt hit a container-acquisition infra failure,
// kernel never executed). Rolling-window column threads.
//
// Measurement round (R4) proved traffic is already ideal (FETCH 36.6 MB,
// WRITE 256 MiB) but the R2 kernel ran at only ~2.5 TB/s (~121 us of the
// 309 us total; ~188 us is fixed harness fill/overhead): one-shot threads,
// 6 redundant loads per output pair, stores serialized behind a fresh
// load-latency wait. Here each thread owns a (n, ox, c4) column and walks
// 16 j's, keeping the two live x-interpolated rows in registers:
//   - 2 loads + 2 stores per output row-pair (was 6 + 2)
//   - x-interp once per input row (was 3x)
//   - unroll-4 loop -> loads for next rows pipeline across iterations
//   - grid 2048 blocks x 256 thr = exact full co-residency (32 waves/CU)
// Edge semantics unchanged: even(2j) = 0.25*row(j-1) + 0.75*row(j), clamped;
// odd(2j+1) = 0.75*row(j) + 0.25*row(j+1), clamped — matches reference.

#define IH 256
#define IW 256
#define OHW 512
#define C4 8        // 32 channels / 4 floats per float4
#define JPER 16     // j's (output row-pairs) per thread

typedef float f4 __attribute__((ext_vector_type(4)));

__global__ __launch_bounds__(256, 8) void bilinear2x_kernel(
    const float* __restrict__ img, float* __restrict__ out) {
    // grid decode: 2048 blocks = oxchunk(16) x jchunk(16) x n(8)
    unsigned bx  = blockIdx.x;
    unsigned oxc = bx & 15u;
    unsigned jc  = (bx >> 4) & 15u;
    unsigned n   = bx >> 8;

    unsigned c4  = threadIdx.x & (C4 - 1);
    unsigned oxl = threadIdx.x >> 3;            // 0..31
    unsigned ox  = oxc * 32u + oxl;
    int j0 = (int)(jc * JPER);

    // x weights: gx = max(0.5*ox - 0.25, 0)
    float gx = fmaxf(0.5f * (float)ox - 0.25f, 0.0f);
    int x0 = (int)gx;
    float w0 = gx - (float)x0;
    int x1 = x0 + (x0 < IW - 1);
    float w1 = 1.0f - w0;

    const f4* base = (const f4*)img + (size_t)n * (IH * IW * C4);
    size_t o0 = (size_t)x0 * C4 + c4;
    size_t o1 = (size_t)x1 * C4 + c4;

    // prologue: x-interp rows j0-1 (clamped) and j0
    int rA = j0 - 1; if (rA < 0) rA = 0;
    const f4* pA = base + (size_t)rA * (IW * C4);
    const f4* pB = base + (size_t)j0 * (IW * C4);
    f4 a0 = pA[o0], a1 = pA[o1];
    f4 b0 = pB[o0], b1 = pB[o1];
    f4 xa = w1 * a0 + w0 * a1;   // x-interp of row j-1
    f4 xb = w1 * b0 + w0 * b1;   // x-interp of row j

    f4* ob = (f4*)out;
    size_t oe = (((size_t)n * OHW + 2 * (size_t)j0) * OHW + ox) * C4 + c4;
    const size_t rowstep = (size_t)OHW * C4;

#pragma unroll 4
    for (int t = 0; t < JPER; ++t) {
        int j = j0 + t;
        int rC = j + 1; if (rC > IH - 1) rC = IH - 1;
        const f4* pC = base + (size_t)rC * (IW * C4);
        f4 cc0 = pC[o0], cc1 = pC[o1];
        f4 xc = w1 * cc0 + w0 * cc1;             // x-interp of row j+1

        f4 re = 0.25f * xa + 0.75f * xb;         // oy = 2j
        f4 ro = 0.75f * xb + 0.25f * xc;         // oy = 2j+1
        ob[oe] = re;
        ob[oe + rowstep] = ro;
        oe += 2 * rowstep;

        xa = xb; xb = xc;                        // roll the window
    }
}

extern "C" void kernel_launch(void* const* d_in, const int* in_sizes, int n_in,
                              void* d_out, int out_size, void* d_ws, size_t ws_size,
                              hipStream_t stream) {
    const float* img = (const float*)d_in[0];
    float* out = (float*)d_out;
    // 8(n) * 16(jchunk) * 16(oxchunk) = 2048 blocks of 256 threads
    dim3 grid(2048);
    dim3 block(256);
    bilinear2x_kernel<<<grid, block, 0, stream>>>(img, out);
}